// Round 4
// baseline (281.491 us; speedup 1.0000x reference)
//
#include <hip/hip_runtime.h>
#include <hip/hip_bf16.h>
#include <stdint.h>

// Problem constants
#define D    2048
#define H    16
#define HD   128
#define KV   4096
#define NCH  64            // matvec row-chunks (32 rows each)
#define RPC  (D / NCH)     // rows per chunk = 32
#define AVCH 64            // AV kk-chunks
#define AVR  (KV / AVCH)   // 64 rows per AV chunk
#define RSQRT_HD 0.08838834764831845f

typedef __attribute__((ext_vector_type(4))) float floatx4;

// ---------------- ws layout (floats) ----------------
// Q=2048, KN=4096, VN=6144, ATT=8192(+65536), VALUES=73728,
// AOUT=75776, X1=77824, H1=79872, H2=81920, PART=83968(+3*64*2048)
// -> total ~477k floats (~1.9 MB)

// part[(m*NCH + chunk)*D + col] = sum_{r in chunk} xin[r] * W[r*D + col]
__global__ void k_matvec_part(const float* __restrict__ W0,
                              const float* __restrict__ W1p,
                              const float* __restrict__ W2p,
                              const float* __restrict__ xin,
                              float* __restrict__ part) {
    const float* W = (blockIdx.y == 0) ? W0 : (blockIdx.y == 1 ? W1p : W2p);
    int c0 = threadIdx.x * 4;          // cols c0..c0+3 and c0+1024..+1027
    int r0 = blockIdx.x * RPC;
    floatx4 a0 = {0.f, 0.f, 0.f, 0.f};
    floatx4 a1 = {0.f, 0.f, 0.f, 0.f};
    for (int r = r0; r < r0 + RPC; ++r) {
        float xv = xin[r];
        floatx4 w0 = *reinterpret_cast<const floatx4*>(W + (size_t)r * D + c0);
        floatx4 w1 = *reinterpret_cast<const floatx4*>(W + (size_t)r * D + c0 + 1024);
        a0 += xv * w0;
        a1 += xv * w1;
    }
    float* p = part + ((size_t)blockIdx.y * NCH + blockIdx.x) * D;
    *reinterpret_cast<floatx4*>(p + c0) = a0;
    *reinterpret_cast<floatx4*>(p + c0 + 1024) = a1;
}

__global__ void k_qkv_reduce(const float* __restrict__ part,
                             const float* __restrict__ bq,
                             const float* __restrict__ bk,
                             const float* __restrict__ bv,
                             float* __restrict__ q, float* __restrict__ kn,
                             float* __restrict__ vn) {
    int t = blockIdx.x * 256 + threadIdx.x;      // 0..6143
    int m = t >> 11;
    int col = t & (D - 1);
    float s = 0.f;
    const float* p = part + (size_t)m * NCH * D + col;
    for (int c = 0; c < NCH; ++c) s += p[(size_t)c * D];
    if (m == 0)      q[col]  = s + bq[col];
    else if (m == 1) kn[col] = s + bk[col];
    else             vn[col] = s + bv[col];
}

// One wave per output row kk: roll V and K caches, compute mask + 16 head logits.
__global__ void k_roll_logits(const float* __restrict__ cache1,
                              const float* __restrict__ cache2,
                              const float* __restrict__ q,
                              const float* __restrict__ kn,
                              const float* __restrict__ vn,
                              float* __restrict__ outv,
                              float* __restrict__ outk,
                              float* __restrict__ att) {
    int wave = threadIdx.x >> 6;
    int lane = threadIdx.x & 63;
    int kk = blockIdx.x * 4 + wave;              // 0..4095
    float pc[8];
    bool nz = false;

    if (kk < KV - 1) {
        const float* vsrc = cache1 + (size_t)(kk + 1) * D;
        const float* ksrc = cache2 + (size_t)(kk + 1) * D;
        float* vdst = outv + (size_t)kk * D;
        float* kdst = outk + (size_t)kk * D;
#pragma unroll
        for (int c = 0; c < 8; ++c) {
            int e = c * 256 + lane * 4;
            floatx4 v4 = *reinterpret_cast<const floatx4*>(vsrc + e);
            *reinterpret_cast<floatx4*>(vdst + e) = v4;
            nz = nz | (v4[0] != 0.f) | (v4[1] != 0.f) | (v4[2] != 0.f) | (v4[3] != 0.f);
            floatx4 k4 = *reinterpret_cast<const floatx4*>(ksrc + e);
            *reinterpret_cast<floatx4*>(kdst + e) = k4;
            floatx4 q4 = *reinterpret_cast<const floatx4*>(q + e);
            pc[c] = q4[0]*k4[0] + q4[1]*k4[1] + q4[2]*k4[2] + q4[3]*k4[3];
        }
    } else {
        float* vdst = outv + (size_t)kk * D;
        float* kdst = outk + (size_t)kk * D;
#pragma unroll
        for (int c = 0; c < 8; ++c) {
            int e = c * 256 + lane * 4;
            floatx4 v4, k4;
#pragma unroll
            for (int j = 0; j < 4; ++j) {
                v4[j] = vn[e + j];
                k4[j] = kn[e + j];
            }
            *reinterpret_cast<floatx4*>(vdst + e) = v4;
            *reinterpret_cast<floatx4*>(kdst + e) = k4;
            nz = nz | (v4[0] != 0.f) | (v4[1] != 0.f) | (v4[2] != 0.f) | (v4[3] != 0.f);
            floatx4 q4 = *reinterpret_cast<const floatx4*>(q + e);
            pc[c] = q4[0]*k4[0] + q4[1]*k4[1] + q4[2]*k4[2] + q4[3]*k4[3];
        }
    }

    unsigned long long bal = __ballot(nz ? 1 : 0);
    bool anynz = (bal != 0ULL);

    // Each chunk c covers heads 2c (lanes 0..31) and 2c+1 (lanes 32..63).
#pragma unroll
    for (int c = 0; c < 8; ++c) {
        float v = pc[c];
        v += __shfl_xor(v, 1);
        v += __shfl_xor(v, 2);
        v += __shfl_xor(v, 4);
        v += __shfl_xor(v, 8);
        v += __shfl_xor(v, 16);
        pc[c] = v;
    }
    if ((lane & 31) == 0) {
        int hi = lane >> 5;
#pragma unroll
        for (int c = 0; c < 8; ++c) {
            int h = c * 2 + hi;
            att[(size_t)h * KV + kk] = anynz ? pc[c] * RSQRT_HD : -INFINITY;
        }
    }
}

__global__ void k_softmax(float* __restrict__ att) {
    __shared__ float sred[4];
    int h = blockIdx.x;
    float* a = att + (size_t)h * KV;
    int t = threadIdx.x;
    float v[16];
    float m = -INFINITY;
#pragma unroll
    for (int i = 0; i < 16; ++i) {
        v[i] = a[i * 256 + t];
        m = fmaxf(m, v[i]);
    }
    for (int s = 32; s >= 1; s >>= 1) m = fmaxf(m, __shfl_xor(m, s));
    if ((t & 63) == 0) sred[t >> 6] = m;
    __syncthreads();
    m = fmaxf(fmaxf(sred[0], sred[1]), fmaxf(sred[2], sred[3]));
    __syncthreads();
    float sum = 0.f;
#pragma unroll
    for (int i = 0; i < 16; ++i) {
        v[i] = __expf(v[i] - m);
        sum += v[i];
    }
    for (int s = 32; s >= 1; s >>= 1) sum += __shfl_xor(sum, s);
    if ((t & 63) == 0) sred[t >> 6] = sum;
    __syncthreads();
    sum = sred[0] + sred[1] + sred[2] + sred[3];
    float inv = 1.0f / sum;
#pragma unroll
    for (int i = 0; i < 16; ++i) a[i * 256 + t] = v[i] * inv;
}

// pav[chunk*D + h*HD + d] = sum_{kk in chunk} att[h,kk] * v[kk,h,d]
__global__ void k_av_part(const float* __restrict__ outv,
                          const float* __restrict__ att,
                          float* __restrict__ pav) {
    int h = blockIdx.y;
    int c = blockIdx.x;
    int lane = threadIdx.x;                      // 0..63
    int dg = (lane & 31) * 4;
    int ks = lane >> 5;                          // 0..1
    floatx4 acc = {0.f, 0.f, 0.f, 0.f};
    int kk0 = c * AVR;
    for (int i = 0; i < AVR / 2; ++i) {
        int kk = kk0 + i * 2 + ks;
        float a = att[(size_t)h * KV + kk];
        floatx4 v4 = *reinterpret_cast<const floatx4*>(outv + (size_t)kk * D + h * HD + dg);
        acc += a * v4;
    }
#pragma unroll
    for (int j = 0; j < 4; ++j) acc[j] += __shfl_xor(acc[j], 32);
    if (lane < 32) {
        *reinterpret_cast<floatx4*>(pav + (size_t)c * D + h * HD + dg) = acc;
    }
}

__global__ void k_av_reduce(const float* __restrict__ pav, float* __restrict__ values) {
    int e = blockIdx.x * 256 + threadIdx.x;
    float s = 0.f;
    for (int c = 0; c < AVCH; ++c) s += pav[(size_t)c * D + e];
    values[e] = s;
}

__global__ void k_mv_reduce(const float* __restrict__ part,
                            const float* __restrict__ bias,
                            float* __restrict__ out, int relu) {
    int col = blockIdx.x * 256 + threadIdx.x;
    float s = 0.f;
    for (int c = 0; c < NCH; ++c) s += part[(size_t)c * D + col];
    s += bias[col];
    if (relu) s = fmaxf(s, 0.0f);
    out[col] = s;
}

// out = LN(a+b)*scale + bias  (fp32 in, fp32 out)
__global__ void k_ln(const float* __restrict__ a, const float* __restrict__ b,
                     const float* __restrict__ sc, const float* __restrict__ bi,
                     float* __restrict__ out) {
    __shared__ float sred[4];
    int t = threadIdx.x;
    float loc[8];
    float s = 0.f;
#pragma unroll
    for (int i = 0; i < 8; ++i) {
        int e = i * 256 + t;
        float v = a[e] + b[e];
        loc[i] = v;
        s += v;
    }
    for (int m = 32; m >= 1; m >>= 1) s += __shfl_xor(s, m);
    if ((t & 63) == 0) sred[t >> 6] = s;
    __syncthreads();
    float mean = (sred[0] + sred[1] + sred[2] + sred[3]) * (1.0f / D);
    __syncthreads();
    float vs = 0.f;
#pragma unroll
    for (int i = 0; i < 8; ++i) {
        float d = loc[i] - mean;
        vs += d * d;
    }
    for (int m = 32; m >= 1; m >>= 1) vs += __shfl_xor(vs, m);
    if ((t & 63) == 0) sred[t >> 6] = vs;
    __syncthreads();
    float var = (sred[0] + sred[1] + sred[2] + sred[3]) * (1.0f / D);
    float inv = 1.0f / sqrtf(var + 1e-6f);
#pragma unroll
    for (int i = 0; i < 8; ++i) {
        int e = i * 256 + t;
        out[e] = (loc[i] - mean) * inv * sc[e] + bi[e];
    }
}

extern "C" void kernel_launch(void* const* d_in, const int* in_sizes, int n_in,
                              void* d_out, int out_size, void* d_ws, size_t ws_size,
                              hipStream_t stream) {
    const float* x      = (const float*)d_in[0];
    const float* cache1 = (const float*)d_in[1];
    const float* cache2 = (const float*)d_in[2];
    const float* Wv     = (const float*)d_in[3];
    const float* bv     = (const float*)d_in[4];
    const float* Wq     = (const float*)d_in[5];
    const float* bq     = (const float*)d_in[6];
    const float* Wk     = (const float*)d_in[7];
    const float* bk     = (const float*)d_in[8];
    const float* Wo     = (const float*)d_in[9];
    const float* bo     = (const float*)d_in[10];
    const float* W1     = (const float*)d_in[11];
    const float* b1     = (const float*)d_in[12];
    const float* W2     = (const float*)d_in[13];
    const float* b2     = (const float*)d_in[14];
    const float* l1s    = (const float*)d_in[15];
    const float* l1b    = (const float*)d_in[16];
    const float* l2s    = (const float*)d_in[17];
    const float* l2b    = (const float*)d_in[18];

    float* out   = (float*)d_out;
    float* outx2 = out;
    float* outv  = out + D;
    float* outk  = out + D + (size_t)KV * D;

    float* w      = (float*)d_ws;
    float* q      = w + 2048;
    float* kn     = w + 4096;
    float* vn     = w + 6144;
    float* att    = w + 8192;
    float* values = w + 73728;
    float* aout   = w + 75776;
    float* x1     = w + 77824;
    float* h1     = w + 79872;
    float* h2     = w + 81920;
    float* part   = w + 83968;
    float* pav    = w + 477184;

    k_matvec_part<<<dim3(NCH, 3), 256, 0, stream>>>(Wq, Wk, Wv, x, part);
    k_qkv_reduce<<<24, 256, 0, stream>>>(part, bq, bk, bv, q, kn, vn);
    k_roll_logits<<<KV / 4, 256, 0, stream>>>(cache1, cache2, q, kn, vn, outv, outk, att);
    k_softmax<<<H, 256, 0, stream>>>(att);
    k_av_part<<<dim3(AVCH, H), 64, 0, stream>>>(outv, att, pav);
    k_av_reduce<<<8, 256, 0, stream>>>(pav, values);
    k_matvec_part<<<dim3(NCH, 1), 256, 0, stream>>>(Wo, Wo, Wo, values, part);
    k_mv_reduce<<<8, 256, 0, stream>>>(part, bo, aout, 0);
    k_ln<<<1, 256, 0, stream>>>(x, aout, l1s, l1b, x1);
    k_matvec_part<<<dim3(NCH, 1), 256, 0, stream>>>(W1, W1, W1, x1, part);
    k_mv_reduce<<<8, 256, 0, stream>>>(part, b1, h1, 1);
    k_matvec_part<<<dim3(NCH, 1), 256, 0, stream>>>(W2, W2, W2, h1, part);
    k_mv_reduce<<<8, 256, 0, stream>>>(part, b2, h2, 0);
    k_ln<<<1, 256, 0, stream>>>(x1, h2, l2s, l2b, outx2);
}